// Round 2
// baseline (970.043 us; speedup 1.0000x reference)
//
#include <hip/hip_runtime.h>
#include <hip/hip_bf16.h>
#include <stdint.h>

typedef unsigned short u16;
typedef __attribute__((ext_vector_type(8))) unsigned short u16x8;
typedef __attribute__((ext_vector_type(8))) short short8;
typedef __attribute__((ext_vector_type(4))) float f32x4;

#define CB   4
#define CC   256
#define CHW  4096
#define CNQ  4097
#define NQP  150
#define CHID 1024

// ---------------- workspace layout (bytes) ----------------
#define XT_OFF    0ul                                   // bf16 [B][4097][256]
#define ST_OFF    (XT_OFF   + 8390656ul)                // bf16 [256][256] (S^T)
#define EXE_OFF   (ST_OFF   + 131072ul)                 // f32  [B][256]
#define HEAT_OFF  (EXE_OFF  + 4096ul)                   // f32  [B][4096]
#define QID_OFF   (HEAT_OFF + 65536ul)                  // int  [B][160]

__device__ __forceinline__ float b2f(u16 x){
  unsigned u = ((unsigned)x) << 16; float f; __builtin_memcpy(&f, &u, 4); return f;
}
__device__ __forceinline__ u16 f2b(float f){
  __hip_bfloat16 h = __float2bfloat16(f); u16 r; __builtin_memcpy(&r, &h, 2); return r;
}
__device__ __forceinline__ f32x4 mfma16(u16x8 a, u16x8 b, f32x4 c){
  short8 as, bs; __builtin_memcpy(&as, &a, 16); __builtin_memcpy(&bs, &b, 16);
  return __builtin_amdgcn_mfma_f32_16x16x32_bf16(as, bs, c, 0, 0, 0);
}
__device__ __forceinline__ u16x8 zero8(){
  u16x8 v;
  #pragma unroll
  for (int e = 0; e < 8; e++) v[e] = 0;
  return v;
}
__device__ __forceinline__ u16x8 cvt8(f32x4 a, f32x4 b){
  u16x8 v;
  v[0]=f2b(a[0]); v[1]=f2b(a[1]); v[2]=f2b(a[2]); v[3]=f2b(a[3]);
  v[4]=f2b(b[0]); v[5]=f2b(b[1]); v[6]=f2b(b[2]); v[7]=f2b(b[3]);
  return v;
}

// ---------------- K0: exemplar mean (f32 in) ----------------
__global__ void exe_prep_k(const float* __restrict__ exe, float* __restrict__ exeF,
                           u16* __restrict__ Xt){
  int b = blockIdx.x, c = threadIdx.x;
  const float* p = exe + (b*CC + c)*49;
  float s = 0.f;
  for (int i = 0; i < 49; i++) s += p[i];
  float m = s / 49.f;
  exeF[b*CC + c] = m;
  Xt[(size_t)b*CNQ*CC + (size_t)CHW*CC + c] = f2b(m);
}

// ---------------- K1: 64x64 tiled transpose, f32 src -> bf16 dst -------------
__global__ void transpose64_k(const float* __restrict__ src, u16* __restrict__ dst,
                              int srcLd, long srcBatch, int dstLd, long dstBatch){
  __shared__ u16 tile[64][72];
  int c0 = blockIdx.x*64, m0 = blockIdx.y*64, b = blockIdx.z;
  const float* S = src + (long)b*srcBatch;
  u16* D = dst + (long)b*dstBatch;
  int t = threadIdx.x;
  int r = t >> 2, q = t & 3;
  for (int uu = q; uu < 8; uu += 4){
    const float* p = S + (long)(c0+r)*srcLd + m0 + uu*8;
    f32x4 a0 = *(const f32x4*)p;
    f32x4 a1 = *(const f32x4*)(p + 4);
    *(u16x8*)&tile[r][uu*8] = cvt8(a0, a1);
  }
  __syncthreads();
  for (int uu = q; uu < 8; uu += 4){
    u16x8 v;
    #pragma unroll
    for (int e = 0; e < 8; e++) v[e] = tile[uu*8 + e][r];
    *(u16x8*)(D + (long)(m0+r)*dstLd + c0 + uu*8) = v;
  }
}

// ---------------- K2: self-contained heat: exe-mean -> z -> heat -> hm -------
__global__ void heat2_k(const float* __restrict__ exe, const float* __restrict__ S,
                        const float* __restrict__ imgf,
                        float* __restrict__ heat, float* __restrict__ out_img){
  int b = blockIdx.y;
  int t = threadIdx.x;
  __shared__ float em[CC];
  __shared__ float zl[CC];
  {
    const float* p = exe + ((long)b*CC + t)*49;
    float s = 0.f;
    for (int i = 0; i < 49; i++) s += p[i];
    em[t] = s / 49.f;
  }
  __syncthreads();
  {
    const float* Sr = S + (long)t*CC;
    float s = 0.f;
    for (int d = 0; d < CC; d++) s += Sr[d] * em[d];
    zl[t] = s;
  }
  __syncthreads();
  int m = blockIdx.x*256 + t;
  const float* base = imgf + (long)b*CC*CHW + m;
  float s = 0.f;
  for (int c = 0; c < CC; c++) s += base[(long)c*CHW] * zl[c];
  heat[b*CHW + m] = s;
  out_img[(long)b*257*CHW + (long)256*CHW + m] = s;
}

// ---------------- K3: NMS + top-150 (bitonic, value desc / index asc) --------
__global__ __launch_bounds__(1024) void topk_k(const float* __restrict__ heat,
                                               int* __restrict__ qids,
                                               float* __restrict__ qbuf,
                                               float* __restrict__ out_coords){
  int b = blockIdx.x, t = threadIdx.x;
  __shared__ unsigned long long sk[4096];
  const float* hb = heat + (long)b*CHW;
  for (int p = t; p < 4096; p += 1024){
    int i = p >> 6, j = p & 63;
    float h = hb[p];
    bool ismax = false;
    if (i >= 1 && i < 63 && j >= 1 && j < 63){
      ismax = (h >= hb[p+64]) && (h > hb[p-64]) && (h >= hb[p+1]) && (h > hb[p-1]);
    }
    float sup = ismax ? h : (h - 1e9f);
    unsigned u = __float_as_uint(sup);
    u = (u & 0x80000000u) ? ~u : (u | 0x80000000u);
    unsigned long long key = ((unsigned long long)u << 32) | (unsigned)(0xFFFFFFFFu - (unsigned)p);
    sk[p] = ~key;                       // ascending sort of ~key == desired order
  }
  __syncthreads();
  for (int k = 2; k <= 4096; k <<= 1){
    for (int j = k >> 1; j > 0; j >>= 1){
      for (int tt = t; tt < 2048; tt += 1024){
        int i1 = 2*tt - (tt & (j-1));
        int i2 = i1 + j;
        unsigned long long a = sk[i1], c = sk[i2];
        bool up = ((i1 & k) == 0);
        if (up ? (a > c) : (a < c)){ sk[i1] = c; sk[i2] = a; }
      }
      __syncthreads();
    }
  }
  if (t < NQP){
    unsigned long long key = ~sk[t];
    int p = (int)(0xFFFFFFFFu - (unsigned)(key & 0xFFFFFFFFull));
    qids[b*160 + t] = p;
    out_coords[((long)b*NQP + t)*2 + 0] = (float)(p >> 6);
    out_coords[((long)b*NQP + t)*2 + 1] = (float)(p & 63);
    qbuf[((long)b*NQP + t)*257 + 256] = hb[p];
  }
}

// ---------------- K4: MFMA flash attention + output assembly -----------------
// 512 threads = 8 waves = 4 M-waves x 2 N-halves; wave-local online softmax,
// end-of-kernel flash-decoding merge. Mask packed to u8 in LDS -> 78,848 B
// total LDS -> 2 blocks/CU (4 waves/SIMD) for cross-block latency hiding.
__global__ __launch_bounds__(512, 4) void flash_k(
    const u16* __restrict__ Xt, const u16* __restrict__ St,
    const float* __restrict__ imgf, const float* __restrict__ maskp,
    const float* __restrict__ Wv, const int* __restrict__ qids,
    float* __restrict__ out_img, float* __restrict__ qbuf){
  // LDS carve:
  //   [0,32768)      kp_tile  u16[64][256]  : Q round-trip / K-tile / final T
  //   [32768,65536)  kt_tile  u16[256][64]  : V^T tile [c][n]
  //   [65536,73728)  p_tile   u16[64][64]   : P tile (per-wave private)
  //   [73728,77824)  maskb    u8[4096]      : mask row (aliased as qid list)
  //   [77824,78848)  mlx      f32[4][2][16][2] : (m,l) exchange for merge
  __shared__ __align__(16) char smem[78848];
  u16*   kp_tile = (u16*)smem;
  u16*   kt_tile = (u16*)(smem + 32768);
  u16*   p_tile  = (u16*)(smem + 65536);
  unsigned char* maskb = (unsigned char*)(smem + 73728);
  float* mlx     = (float*)(smem + 77824);

  int b = blockIdx.y;
  int m0 = blockIdx.x*64;
  int t = threadIdx.x;
  int lane = t & 63, l15 = lane & 15, qd = lane >> 4;
  int w = t >> 6, wm = w & 3, wn = w >> 2;
  f32x4 zero4 = {0.f,0.f,0.f,0.f};

  // ---- stage mask row into LDS as packed u8 (512 thr x 8 px) ----
  {
    const float* mp = maskp + (long)b*CHW + t*8;
    f32x4 a0 = *(const f32x4*)mp;
    f32x4 a1 = *(const f32x4*)(mp + 4);
    unsigned long long pk = 0;
    #pragma unroll
    for (int e = 0; e < 4; e++){
      pk |= (unsigned long long)(a0[e] == 1.0f ? 1u : 0u) << (8*e);
      pk |= (unsigned long long)(a1[e] == 1.0f ? 1u : 0u) << (8*(e+4));
    }
    *(unsigned long long*)&maskb[t*8] = pk;
  }

  // ---- Phase 0: Q[64][256] = Xrows · St^T; wave (wm,wn) computes col half wn
  {
    f32x4 D[8];
    #pragma unroll
    for (int i = 0; i < 8; i++) D[i] = zero4;
    const u16* arow = Xt + ((long)b*CNQ + (m0 + wm*16 + l15))*CC;
    #pragma unroll
    for (int ks = 0; ks < 8; ks++){
      u16x8 af = *(const u16x8*)(arow + ks*32 + qd*8);
      #pragma unroll
      for (int ds = 0; ds < 8; ds++){
        int dsg = wn*8 + ds;
        u16x8 bf_ = *(const u16x8*)(St + (long)(dsg*16 + l15)*CC + ks*32 + qd*8);
        D[ds] = mfma16(af, bf_, D[ds]);
      }
    }
    #pragma unroll
    for (int ds = 0; ds < 8; ds++){
      #pragma unroll
      for (int r = 0; r < 4; r++){
        int prow = wm*16 + qd*4 + r;
        int ccol = (wn*8 + ds)*16 + l15;
        kp_tile[prow*256 + ((ccol >> 3) ^ ((prow & 7)*4))*8 + (ccol & 7)] = f2b(D[ds][r]);
      }
    }
  }
  __syncthreads();
  u16x8 afrag[8];
  {
    int arl = wm*16 + l15;
    #pragma unroll
    for (int ks = 0; ks < 8; ks++)
      afrag[ks] = *(const u16x8*)&kp_tile[arl*256 + (((ks*4 + qd)) ^ ((arl & 7)*4))*8];
  }
  int rowAllowed[4];
  float mi[4], li[4];
  #pragma unroll
  for (int r = 0; r < 4; r++){
    int m = m0 + wm*16 + qd*4 + r;
    rowAllowed[r] = maskb[m];
    mi[r] = -1e30f; li[r] = 0.f;
  }
  f32x4 O[16];
  #pragma unroll
  for (int i = 0; i < 16; i++) O[i] = zero4;
  __syncthreads();   // afrag reads done before staging overwrites kp_tile

  int srow = t >> 3, su = t & 7;   // K staging: 64 rows x 8 threads
  int vu = t & 7;                  // V staging

  for (int nt = 0; nt < 65; nt++){
    int n0 = nt*64;
    // ---- stage K tile (Xt rows n0..n0+63; row 4096 valid, beyond zero) ----
    {
      const u16* xrow = Xt + ((long)b*CNQ + (n0 + srow))*CC;
      bool valid = (n0 + srow) < CNQ;
      #pragma unroll
      for (int i = 0; i < 4; i++){
        int uu = su + 8*i;
        int pu = uu ^ ((srow & 7)*4);
        u16x8 v = zero8();
        if (valid) v = *(const u16x8*)(xrow + uu*8);
        *(u16x8*)&kp_tile[srow*256 + pu*8] = v;
      }
      // ---- stage V^T tile [c][n] from f32 img; last tile: col0 = exemplar ----
      bool nvalid = (n0 + 63) < CHW;
      #pragma unroll
      for (int j = 0; j < 4; j++){
        int c = (t >> 3) + 64*j;
        int pu2 = vu ^ (c & 7);
        u16x8 v = zero8();
        if (nvalid){
          const float* crow = imgf + ((long)b*CC + c)*CHW + n0 + vu*8;
          f32x4 a0 = *(const f32x4*)crow;
          f32x4 a1 = *(const f32x4*)(crow + 4);
          v = cvt8(a0, a1);
        } else if (vu == 0){
          v[0] = Xt[((long)b*CNQ + CHW)*CC + c];
        }
        *(u16x8*)&kt_tile[c*64 + pu2*8] = v;
      }
    }
    __syncthreads();   // (1) tiles ready

    // ---- QK^T (this wave's 32-column half) ----
    f32x4 sc[2];
    sc[0] = zero4; sc[1] = zero4;
    #pragma unroll
    for (int ks = 0; ks < 8; ks++){
      #pragma unroll
      for (int ns = 0; ns < 2; ns++){
        int n_l = (wn*2 + ns)*16 + l15;
        u16x8 bfrag = *(const u16x8*)&kp_tile[n_l*256 + (((ks*4 + qd)) ^ ((n_l & 7)*4))*8];
        sc[ns] = mfma16(afrag[ks], bfrag, sc[ns]);
      }
    }

    // ---- mask bias + online softmax (wave-local, own half) ----
    float sEff[2][4];
    #pragma unroll
    for (int ns = 0; ns < 2; ns++){
      int n = n0 + (wn*2 + ns)*16 + l15;
      bool inv = (n >= CNQ);
      bool isEx = (n == CHW);
      int cm = 0;
      if (!inv && !isEx) cm = maskb[n];
      #pragma unroll
      for (int r = 0; r < 4; r++){
        float s = sc[ns][r];
        float se;
        if (inv)        se = -1e30f;
        else if (isEx)  se = s;
        else            se = (rowAllowed[r] & cm) ? s : s - 1e9f;
        sEff[ns][r] = se;
      }
    }
    float al[4], nm[4];
    #pragma unroll
    for (int r = 0; r < 4; r++){
      float tm = fmaxf(sEff[0][r], sEff[1][r]);
      #pragma unroll
      for (int d = 1; d < 16; d <<= 1) tm = fmaxf(tm, __shfl_xor(tm, d, 16));
      float newm = fmaxf(mi[r], tm);
      al[r] = (mi[r] < -1e29f) ? 0.f : __expf(fmaxf(mi[r] - newm, -88.f));
      nm[r] = newm; mi[r] = newm;
    }
    #pragma unroll
    for (int r = 0; r < 4; r++){
      float rs = 0.f;
      int prow = wm*16 + qd*4 + r;
      #pragma unroll
      for (int ns = 0; ns < 2; ns++){
        float p = __expf(fmaxf(sEff[ns][r] - nm[r], -88.f));
        rs += p;
        int ccol = (wn*2 + ns)*16 + l15;
        p_tile[prow*64 + ((ccol >> 3) ^ (prow & 7))*8 + (ccol & 7)] = f2b(p);
      }
      #pragma unroll
      for (int d = 1; d < 16; d <<= 1) rs += __shfl_xor(rs, d, 16);
      li[r] = li[r]*al[r] + rs;
    }
    // P writes/reads are wave-private regions: no barrier, just drain LDS.
    asm volatile("s_waitcnt lgkmcnt(0)" ::: "memory");

    // ---- rescale T, then T += P·Vtile over this wave's 32-column half ----
    #pragma unroll
    for (int ds = 0; ds < 16; ds++){
      #pragma unroll
      for (int r = 0; r < 4; r++) O[ds][r] *= al[r];
    }
    {
      int prow2 = wm*16 + l15;
      u16x8 pf = *(const u16x8*)&p_tile[prow2*64 + (((wn*4 + qd)) ^ (prow2 & 7))*8];
      #pragma unroll
      for (int ds = 0; ds < 16; ds++){
        int c = ds*16 + l15;
        u16x8 vf = *(const u16x8*)&kt_tile[c*64 + (((wn*4 + qd)) ^ (c & 7))*8];
        O[ds] = mfma16(pf, vf, O[ds]);
      }
    }
    __syncthreads();   // (2) reads done before next staging
  }

  // ---- merge the two N-halves (flash-decoding in-block merge) ----
  int* qlds = (int*)maskb;            // mask no longer needed
  if (t < NQP) qlds[t] = qids[b*160 + t];
  if (l15 == 0){
    #pragma unroll
    for (int r = 0; r < 4; r++){
      mlx[(((wm*2 + wn)*16) + qd*4 + r)*2 + 0] = mi[r];
      mlx[(((wm*2 + wn)*16) + qd*4 + r)*2 + 1] = li[r];
    }
  }
  __syncthreads();
  float alpha[4], linv[4];
  #pragma unroll
  for (int r = 0; r < 4; r++){
    float mo = mlx[(((wm*2 + (1 - wn))*16) + qd*4 + r)*2 + 0];
    float lo = mlx[(((wm*2 + (1 - wn))*16) + qd*4 + r)*2 + 1];
    float ms = fmaxf(mi[r], mo);
    float aS = (mi[r] < -1e29f) ? 0.f : __expf(mi[r] - ms);
    float aO = (mo    < -1e29f) ? 0.f : __expf(mo - ms);
    float ls = li[r]*aS + lo*aO;
    alpha[r] = aS;
    linv[r] = (ls > 0.f) ? (1.0f / ls) : 0.f;
  }
  float* Tsum = (float*)smem;         // 64KB f32 scratch spanning kp+kt
  if (wn == 1){
    #pragma unroll
    for (int ds = 0; ds < 16; ds++){
      #pragma unroll
      for (int r = 0; r < 4; r++)
        Tsum[(wm*16 + qd*4 + r)*256 + ds*16 + l15] = O[ds][r]*alpha[r];
    }
  }
  __syncthreads();
  if (wn == 0){
    #pragma unroll
    for (int ds = 0; ds < 16; ds++){
      #pragma unroll
      for (int r = 0; r < 4; r++)
        O[ds][r] = (O[ds][r]*alpha[r] + Tsum[(wm*16 + qd*4 + r)*256 + ds*16 + l15]) * linv[r];
    }
  }
  __syncthreads();                    // Tsum reads done before bf16 overwrite
  if (wn == 0){
    #pragma unroll
    for (int ds = 0; ds < 16; ds++){
      #pragma unroll
      for (int r = 0; r < 4; r++){
        int prow = wm*16 + qd*4 + r;
        int ccol = ds*16 + l15;
        kp_tile[prow*256 + ((ccol >> 3) ^ ((prow & 7)*4))*8 + (ccol & 7)] = f2b(O[ds][r]);
      }
    }
  }
  __syncthreads();
  u16x8 tfrag[8];
  {
    int arl = wm*16 + l15;
    #pragma unroll
    for (int ks = 0; ks < 8; ks++)
      tfrag[ks] = *(const u16x8*)&kp_tile[arl*256 + (((ks*4 + qd)) ^ ((arl & 7)*4))*8];
  }
  // ---- final projection F = T_norm · Wv^T, ds split between halves ----
  f32x4 F[8];
  #pragma unroll
  for (int i = 0; i < 8; i++) F[i] = zero4;
  #pragma unroll
  for (int ks = 0; ks < 8; ks++){
    #pragma unroll
    for (int ds = 0; ds < 8; ds++){
      int dsg = wn*8 + ds;
      const float* wr = Wv + (long)(dsg*16 + l15)*CC + ks*32 + qd*8;
      f32x4 w0 = *(const f32x4*)wr;
      f32x4 w1 = *(const f32x4*)(wr + 4);
      F[ds] = mfma16(tfrag[ks], cvt8(w0, w1), F[ds]);
    }
  }

  // ---- epilogue: f32 img_out + f32 query rows (ds-half per wave) ----
  int qix[4];
  #pragma unroll
  for (int r = 0; r < 4; r++){
    int m = m0 + wm*16 + qd*4 + r;
    int f = -1;
    for (int i = 0; i < NQP; i++) if (qlds[i] == m){ f = i; break; }
    qix[r] = f;
  }
  float* oi = out_img + (long)b*257*CHW;
  const float* fi = imgf + (long)b*CC*CHW;
  int mb = m0 + wm*16 + qd*4;
  #pragma unroll
  for (int ds = 0; ds < 8; ds++){
    int d = (wn*8 + ds)*16 + l15;
    f32x4 ivals = *(const f32x4*)(fi + (long)d*CHW + mb);
    f32x4 ovals;
    #pragma unroll
    for (int r = 0; r < 4; r++){
      float v = F[ds][r] + ivals[r];
      ovals[r] = v;
      if (qix[r] >= 0) qbuf[((long)b*NQP + qix[r])*257 + d] = v;
    }
    *(f32x4*)(oi + (long)d*CHW + mb) = ovals;
  }
}

// ---------------- K5: fused LayerNorm + MLP head (all f32) -------------------
// Wave-cooperative GEMV: each wave owns an output row, lanes read the weight
// row CONTIGUOUSLY (coalesced), 6-level shuffle reduce. Replaces the old
// thread-per-row walk whose stride-257/1024 lane pattern touched 64 cache
// lines per wave load.
__global__ __launch_bounds__(256) void qhead_k(float* __restrict__ qbuf,
    const float* __restrict__ g, const float* __restrict__ be,
    const float* __restrict__ W1, const float* __restrict__ b1,
    const float* __restrict__ W2, const float* __restrict__ b2){
  int bi = blockIdx.x;
  int t = threadIdx.x, lane = t & 63, w = t >> 6;
  __shared__ __align__(16) float xl[257];
  __shared__ __align__(16) float hl[CHID];
  __shared__ float r1[4], r2[4];
  float* row = qbuf + (long)bi*257;
  float v0 = row[t];
  float v1 = (t == 0) ? row[256] : 0.f;
  float s = v0 + v1;
  #pragma unroll
  for (int d = 1; d < 64; d <<= 1) s += __shfl_xor(s, d, 64);
  if (lane == 0) r1[w] = s;
  __syncthreads();
  float mu = (r1[0]+r1[1]+r1[2]+r1[3]) / 257.f;
  float d0 = v0 - mu;
  float d1 = (t == 0) ? (v1 - mu) : 0.f;
  float vs = d0*d0 + d1*d1;
  #pragma unroll
  for (int d = 1; d < 64; d <<= 1) vs += __shfl_xor(vs, d, 64);
  if (lane == 0) r2[w] = vs;
  __syncthreads();
  float var = (r2[0]+r2[1]+r2[2]+r2[3]) / 257.f;
  float inv = 1.0f / sqrtf(var + 1e-5f);
  xl[t] = d0*inv*g[t] + be[t];
  if (t == 0) xl[256] = d1*inv*g[256] + be[256];
  __syncthreads();
  float x256 = xl[256];
  // ---- layer 1: wave w computes rows h = w, w+4, ... (coalesced W1 reads) ----
  for (int h = w; h < CHID; h += 4){
    const float* wr = W1 + (long)h*257;
    float acc = 0.f;
    #pragma unroll
    for (int j = 0; j < 4; j++)
      acc += wr[lane + j*64] * xl[lane + j*64];
    if (lane == 0) acc += wr[256] * x256;
    #pragma unroll
    for (int d = 1; d < 64; d <<= 1) acc += __shfl_xor(acc, d, 64);
    if (lane == 0) hl[h] = fmaxf(acc + b1[h], 0.f);
  }
  __syncthreads();
  // ---- layer 2: wave w computes rows o = w, w+4, ... (coalesced W2 reads) ----
  for (int o = w; o < 257; o += 4){
    const float* wr = W2 + (long)o*CHID + lane*4;
    const float* hp = hl + lane*4;
    float acc = 0.f;
    #pragma unroll
    for (int j = 0; j < 4; j++){
      f32x4 wv = *(const f32x4*)(wr + j*256);
      f32x4 hv = *(const f32x4*)(hp + j*256);
      acc += wv[0]*hv[0] + wv[1]*hv[1] + wv[2]*hv[2] + wv[3]*hv[3];
    }
    #pragma unroll
    for (int d = 1; d < 64; d <<= 1) acc += __shfl_xor(acc, d, 64);
    if (lane == 0) row[o] = acc + b2[o];
  }
}

// ---------------- launch: input mapping by SIZE (robust to ordering) ---------
extern "C" void kernel_launch(void* const* d_in, const int* in_sizes, int n_in,
                              void* d_out, int out_size, void* d_ws, size_t ws_size,
                              hipStream_t stream){
  (void)out_size; (void)ws_size;
  int idxImg=-1, idxExe=-1, idxMask=-1, idxB1=-1;
  int idx65[2]={-1,-1}; int n65=0;
  int idx263[2]={-1,-1}; int n263=0;
  int idx257[3]={-1,-1,-1}; int n257=0;
  for (int i = 0; i < n_in; i++){
    int s = in_sizes[i];
    if      (s == 4194304) idxImg = i;
    else if (s == 50176)   idxExe = i;
    else if (s == 16384)   idxMask = i;
    else if (s == 1024)    idxB1 = i;
    else if (s == 65536)  { if (n65 < 2)  idx65[n65++] = i; }
    else if (s == 263168) { if (n263 < 2) idx263[n263++] = i; }
    else if (s == 257)    { if (n257 < 3) idx257[n257++] = i; }
  }
  const float* img  = (const float*)d_in[idxImg];
  const float* exe  = (const float*)d_in[idxExe];
  const float* mask = (const float*)d_in[idxMask];
  const float* S    = (const float*)d_in[idx65[0]];   // S before Wv in both dict & sorted order
  const float* Wv   = (const float*)d_in[idx65[1]];
  const float* W1   = (const float*)d_in[idx263[0]];  // W1 before W2 in both orders
  const float* W2   = (const float*)d_in[idx263[1]];
  const float* b1   = (const float*)d_in[idxB1];
  const float *lng, *lnb, *b2;
  if (idxImg == 0){           // dict order: ln_g, ln_b, b2
    lng = (const float*)d_in[idx257[0]];
    lnb = (const float*)d_in[idx257[1]];
    b2  = (const float*)d_in[idx257[2]];
  } else {                    // name-sorted: b2, ln_b, ln_g
    b2  = (const float*)d_in[idx257[0]];
    lnb = (const float*)d_in[idx257[1]];
    lng = (const float*)d_in[idx257[2]];
  }

  char* ws = (char*)d_ws;
  u16*   Xt   = (u16*)(ws + XT_OFF);
  u16*   St   = (u16*)(ws + ST_OFF);
  float* exeF = (float*)(ws + EXE_OFF);
  float* heat = (float*)(ws + HEAT_OFF);
  int*   qids = (int*)(ws + QID_OFF);

  float* out      = (float*)d_out;                       // f32 outputs
  float* out_img  = out;                                 // [4][257][4096]
  float* qbuf     = out + (size_t)CB*257*CHW;            // [4][150][257]
  float* out_crd  = qbuf + (size_t)CB*NQP*257;           // [4][150][2]

  exe_prep_k<<<dim3(CB), dim3(256), 0, stream>>>(exe, exeF, Xt);
  transpose64_k<<<dim3(4, 64, CB), dim3(256), 0, stream>>>(
      img, Xt, CHW, (long)CC*CHW, CC, (long)CNQ*CC);
  transpose64_k<<<dim3(4, 4, 1), dim3(256), 0, stream>>>(
      S, St, CC, 0, CC, 0);
  heat2_k<<<dim3(16, CB), dim3(256), 0, stream>>>(exe, S, img, heat, out_img);
  topk_k<<<dim3(CB), dim3(1024), 0, stream>>>(heat, qids, qbuf, out_crd);
  flash_k<<<dim3(64, CB), dim3(512), 0, stream>>>(
      Xt, St, img, mask, Wv, qids, out_img, qbuf);
  qhead_k<<<dim3(CB*NQP), dim3(256), 0, stream>>>(qbuf, lng, lnb, W1, b1, W2, b2);
}

// Round 3
// 597.284 us; speedup vs baseline: 1.6241x; 1.6241x over previous
//
#include <hip/hip_runtime.h>
#include <hip/hip_bf16.h>
#include <stdint.h>

typedef unsigned short u16;
typedef __attribute__((ext_vector_type(8))) unsigned short u16x8;
typedef __attribute__((ext_vector_type(8))) short short8;
typedef __attribute__((ext_vector_type(4))) float f32x4;

#define CB   4
#define CC   256
#define CHW  4096
#define CNQ  4097
#define NQP  150
#define CHID 1024

// ---------------- workspace layout (bytes) ----------------
#define XT_OFF    0ul                                   // bf16 [B][4097][256]
#define ST_OFF    (XT_OFF   + 8390656ul)                // bf16 [256][256] (S^T)
#define EXE_OFF   (ST_OFF   + 131072ul)                 // f32  [B][256]
#define HEAT_OFF  (EXE_OFF  + 4096ul)                   // f32  [B][4096]
#define QID_OFF   (HEAT_OFF + 65536ul)                  // int  [B][160]

__device__ __forceinline__ float b2f(u16 x){
  unsigned u = ((unsigned)x) << 16; float f; __builtin_memcpy(&f, &u, 4); return f;
}
__device__ __forceinline__ u16 f2b(float f){
  __hip_bfloat16 h = __float2bfloat16(f); u16 r; __builtin_memcpy(&r, &h, 2); return r;
}
__device__ __forceinline__ f32x4 mfma16(u16x8 a, u16x8 b, f32x4 c){
  short8 as, bs; __builtin_memcpy(&as, &a, 16); __builtin_memcpy(&bs, &b, 16);
  return __builtin_amdgcn_mfma_f32_16x16x32_bf16(as, bs, c, 0, 0, 0);
}
__device__ __forceinline__ u16x8 zero8(){
  u16x8 v;
  #pragma unroll
  for (int e = 0; e < 8; e++) v[e] = 0;
  return v;
}
__device__ __forceinline__ u16x8 cvt8(f32x4 a, f32x4 b){
  u16x8 v;
  v[0]=f2b(a[0]); v[1]=f2b(a[1]); v[2]=f2b(a[2]); v[3]=f2b(a[3]);
  v[4]=f2b(b[0]); v[5]=f2b(b[1]); v[6]=f2b(b[2]); v[7]=f2b(b[3]);
  return v;
}

// ---------------- K0: exemplar mean (f32 in) ----------------
__global__ void exe_prep_k(const float* __restrict__ exe, float* __restrict__ exeF,
                           u16* __restrict__ Xt){
  int b = blockIdx.x, c = threadIdx.x;
  const float* p = exe + (b*CC + c)*49;
  float s = 0.f;
  for (int i = 0; i < 49; i++) s += p[i];
  float m = s / 49.f;
  exeF[b*CC + c] = m;
  Xt[(size_t)b*CNQ*CC + (size_t)CHW*CC + c] = f2b(m);
}

// ---------------- K1: 64x64 tiled transpose, f32 src -> bf16 dst -------------
__global__ void transpose64_k(const float* __restrict__ src, u16* __restrict__ dst,
                              int srcLd, long srcBatch, int dstLd, long dstBatch){
  __shared__ u16 tile[64][72];
  int c0 = blockIdx.x*64, m0 = blockIdx.y*64, b = blockIdx.z;
  const float* S = src + (long)b*srcBatch;
  u16* D = dst + (long)b*dstBatch;
  int t = threadIdx.x;
  int r = t >> 2, q = t & 3;
  for (int uu = q; uu < 8; uu += 4){
    const float* p = S + (long)(c0+r)*srcLd + m0 + uu*8;
    f32x4 a0 = *(const f32x4*)p;
    f32x4 a1 = *(const f32x4*)(p + 4);
    *(u16x8*)&tile[r][uu*8] = cvt8(a0, a1);
  }
  __syncthreads();
  for (int uu = q; uu < 8; uu += 4){
    u16x8 v;
    #pragma unroll
    for (int e = 0; e < 8; e++) v[e] = tile[uu*8 + e][r];
    *(u16x8*)(D + (long)(m0+r)*dstLd + c0 + uu*8) = v;
  }
}

// ---------------- K2: self-contained heat: exe-mean -> z -> heat -> hm -------
__global__ void heat2_k(const float* __restrict__ exe, const float* __restrict__ S,
                        const float* __restrict__ imgf,
                        float* __restrict__ heat, float* __restrict__ out_img){
  int b = blockIdx.y;
  int t = threadIdx.x;
  __shared__ float em[CC];
  __shared__ float zl[CC];
  {
    const float* p = exe + ((long)b*CC + t)*49;
    float s = 0.f;
    for (int i = 0; i < 49; i++) s += p[i];
    em[t] = s / 49.f;
  }
  __syncthreads();
  {
    const float* Sr = S + (long)t*CC;
    float s = 0.f;
    for (int d = 0; d < CC; d++) s += Sr[d] * em[d];
    zl[t] = s;
  }
  __syncthreads();
  int m = blockIdx.x*256 + t;
  const float* base = imgf + (long)b*CC*CHW + m;
  float s = 0.f;
  for (int c = 0; c < CC; c++) s += base[(long)c*CHW] * zl[c];
  heat[b*CHW + m] = s;
  out_img[(long)b*257*CHW + (long)256*CHW + m] = s;
}

// ---------------- K3: NMS + top-150 (bitonic, value desc / index asc) --------
__global__ __launch_bounds__(1024) void topk_k(const float* __restrict__ heat,
                                               int* __restrict__ qids,
                                               float* __restrict__ qbuf,
                                               float* __restrict__ out_coords){
  int b = blockIdx.x, t = threadIdx.x;
  __shared__ unsigned long long sk[4096];
  const float* hb = heat + (long)b*CHW;
  for (int p = t; p < 4096; p += 1024){
    int i = p >> 6, j = p & 63;
    float h = hb[p];
    bool ismax = false;
    if (i >= 1 && i < 63 && j >= 1 && j < 63){
      ismax = (h >= hb[p+64]) && (h > hb[p-64]) && (h >= hb[p+1]) && (h > hb[p-1]);
    }
    float sup = ismax ? h : (h - 1e9f);
    unsigned u = __float_as_uint(sup);
    u = (u & 0x80000000u) ? ~u : (u | 0x80000000u);
    unsigned long long key = ((unsigned long long)u << 32) | (unsigned)(0xFFFFFFFFu - (unsigned)p);
    sk[p] = ~key;                       // ascending sort of ~key == desired order
  }
  __syncthreads();
  for (int k = 2; k <= 4096; k <<= 1){
    for (int j = k >> 1; j > 0; j >>= 1){
      for (int tt = t; tt < 2048; tt += 1024){
        int i1 = 2*tt - (tt & (j-1));
        int i2 = i1 + j;
        unsigned long long a = sk[i1], c = sk[i2];
        bool up = ((i1 & k) == 0);
        if (up ? (a > c) : (a < c)){ sk[i1] = c; sk[i2] = a; }
      }
      __syncthreads();
    }
  }
  if (t < NQP){
    unsigned long long key = ~sk[t];
    int p = (int)(0xFFFFFFFFu - (unsigned)(key & 0xFFFFFFFFull));
    qids[b*160 + t] = p;
    out_coords[((long)b*NQP + t)*2 + 0] = (float)(p >> 6);
    out_coords[((long)b*NQP + t)*2 + 1] = (float)(p & 63);
    qbuf[((long)b*NQP + t)*257 + 256] = hb[p];
  }
}

// ---------------- K4: MFMA flash attention + output assembly -----------------
// 512 threads = 8 waves = 4 M-waves x 2 N-halves; wave-local online softmax,
// end-of-kernel flash-decoding merge. Double-buffered K/V LDS + T14 split
// staging (issue loads early / ds_write late) -> 1 barrier/tile, staging
// latency hidden under MFMA+softmax. launch_bounds(512,2): VGPR~170, no spill
// (the (512,4) experiment forced 64 VGPR -> 280MB spill traffic, 2x slower).
__global__ __launch_bounds__(512, 2) void flash_k(
    const u16* __restrict__ Xt, const u16* __restrict__ St,
    const float* __restrict__ imgf, const float* __restrict__ maskp,
    const float* __restrict__ Wv, const int* __restrict__ qids,
    float* __restrict__ out_img, float* __restrict__ qbuf){
  // LDS carve:
  //   [0,32768)        kp0  u16[64][256]  : K buf0; Q round-trip; final T
  //   [32768,65536)    kt0  u16[256][64]  : V^T buf0
  //   [65536,98304)    kp1  u16[64][256]  : K buf1
  //   [98304,131072)   kt1  u16[256][64]  : V^T buf1
  //   [131072,139264)  p_tile u16[64][64] : P tile (per-wave private)
  //   [139264,143360)  maskb  u8[4096]    : mask row (aliased as qid list)
  //   [143360,144384)  mlx  f32[4][2][16][2] : (m,l) exchange for merge
  //   final merge: Tsum f32[64][256] spans [0,65536) (kp0+kt0)
  __shared__ __align__(16) char smem[144384];
  u16*   kp0 = (u16*)smem;
  u16*   kt0 = (u16*)(smem + 32768);
  u16*   kp1 = (u16*)(smem + 65536);
  u16*   kt1 = (u16*)(smem + 98304);
  u16*   p_tile = (u16*)(smem + 131072);
  unsigned char* maskb = (unsigned char*)(smem + 139264);
  float* mlx = (float*)(smem + 143360);

  int b = blockIdx.y;
  int m0 = blockIdx.x*64;
  int t = threadIdx.x;
  int lane = t & 63, l15 = lane & 15, qd = lane >> 4;
  int w = t >> 6, wm = w & 3, wn = w >> 2;
  f32x4 zero4 = {0.f,0.f,0.f,0.f};

  // ---- stage mask row into LDS as packed u8 (512 thr x 8 px) ----
  {
    const float* mp = maskp + (long)b*CHW + t*8;
    f32x4 a0 = *(const f32x4*)mp;
    f32x4 a1 = *(const f32x4*)(mp + 4);
    unsigned long long pk = 0;
    #pragma unroll
    for (int e = 0; e < 4; e++){
      pk |= (unsigned long long)(a0[e] == 1.0f ? 1u : 0u) << (8*e);
      pk |= (unsigned long long)(a1[e] == 1.0f ? 1u : 0u) << (8*(e+4));
    }
    *(unsigned long long*)&maskb[t*8] = pk;
  }

  // ---- Phase 0: Q[64][256] = Xrows · St^T; wave (wm,wn) computes col half wn
  {
    f32x4 D[8];
    #pragma unroll
    for (int i = 0; i < 8; i++) D[i] = zero4;
    const u16* arow = Xt + ((long)b*CNQ + (m0 + wm*16 + l15))*CC;
    #pragma unroll
    for (int ks = 0; ks < 8; ks++){
      u16x8 af = *(const u16x8*)(arow + ks*32 + qd*8);
      #pragma unroll
      for (int ds = 0; ds < 8; ds++){
        int dsg = wn*8 + ds;
        u16x8 bf_ = *(const u16x8*)(St + (long)(dsg*16 + l15)*CC + ks*32 + qd*8);
        D[ds] = mfma16(af, bf_, D[ds]);
      }
    }
    #pragma unroll
    for (int ds = 0; ds < 8; ds++){
      #pragma unroll
      for (int r = 0; r < 4; r++){
        int prow = wm*16 + qd*4 + r;
        int ccol = (wn*8 + ds)*16 + l15;
        kp0[prow*256 + ((ccol >> 3) ^ ((prow & 7)*4))*8 + (ccol & 7)] = f2b(D[ds][r]);
      }
    }
  }
  __syncthreads();
  u16x8 afrag[8];
  {
    int arl = wm*16 + l15;
    #pragma unroll
    for (int ks = 0; ks < 8; ks++)
      afrag[ks] = *(const u16x8*)&kp0[arl*256 + (((ks*4 + qd)) ^ ((arl & 7)*4))*8];
  }
  int rowAllowed[4];
  float mi[4], li[4];
  #pragma unroll
  for (int r = 0; r < 4; r++){
    int m = m0 + wm*16 + qd*4 + r;
    rowAllowed[r] = maskb[m];
    mi[r] = -1e30f; li[r] = 0.f;
  }
  f32x4 O[16];
  #pragma unroll
  for (int i = 0; i < 16; i++) O[i] = zero4;
  __syncthreads();   // afrag reads done before staging overwrites kp0

  int srow = t >> 3, su = t & 7;   // K staging: 64 rows x 8 threads
  int vu = t & 7;                  // V staging

  u16x8 kreg[4];
  f32x4 vreg[8];
  u16   exv[4];

  // ---- prologue: stage tile 0 into buf0 (all rows/cols valid at nt=0) ----
  {
    const u16* xrow = Xt + ((long)b*CNQ + srow)*CC;
    #pragma unroll
    for (int i = 0; i < 4; i++) kreg[i] = *(const u16x8*)(xrow + (su + 8*i)*8);
    #pragma unroll
    for (int j = 0; j < 4; j++){
      int c = (t >> 3) + 64*j;
      const float* crow = imgf + ((long)b*CC + c)*CHW + vu*8;
      vreg[2*j]   = *(const f32x4*)crow;
      vreg[2*j+1] = *(const f32x4*)(crow + 4);
    }
    #pragma unroll
    for (int i = 0; i < 4; i++){
      int uu = su + 8*i;
      *(u16x8*)&kp0[srow*256 + (uu ^ ((srow & 7)*4))*8] = kreg[i];
    }
    #pragma unroll
    for (int j = 0; j < 4; j++){
      int c = (t >> 3) + 64*j;
      *(u16x8*)&kt0[c*64 + (vu ^ (c & 7))*8] = cvt8(vreg[2*j], vreg[2*j+1]);
    }
  }
  __syncthreads();

  for (int nt = 0; nt < 65; nt++){
    int cur = nt & 1;
    const u16* kpc = cur ? kp1 : kp0;
    const u16* ktc = cur ? kt1 : kt0;
    u16* kpn = cur ? kp0 : kp1;
    u16* ktn = cur ? kt0 : kt1;
    int n0 = nt*64;
    bool havenext = (nt < 64);
    bool nvalid2 = false;

    // ---- ISSUE next tile's global loads (latency hides under compute) ----
    if (havenext){
      int n1 = n0 + 64;
      const u16* xrow = Xt + ((long)b*CNQ + (n1 + srow))*CC;
      bool valid = (n1 + srow) < CNQ;
      #pragma unroll
      for (int i = 0; i < 4; i++)
        kreg[i] = valid ? *(const u16x8*)(xrow + (su + 8*i)*8) : zero8();
      nvalid2 = (n1 + 63) < CHW;
      if (nvalid2){
        #pragma unroll
        for (int j = 0; j < 4; j++){
          int c = (t >> 3) + 64*j;
          const float* crow = imgf + ((long)b*CC + c)*CHW + n1 + vu*8;
          vreg[2*j]   = *(const f32x4*)crow;
          vreg[2*j+1] = *(const f32x4*)(crow + 4);
        }
      } else if (vu == 0){
        #pragma unroll
        for (int j = 0; j < 4; j++){
          int c = (t >> 3) + 64*j;
          exv[j] = Xt[((long)b*CNQ + CHW)*CC + c];
        }
      }
    }

    // ---- QK^T (this wave's 32-column half) on buf[cur] ----
    f32x4 sc[2];
    sc[0] = zero4; sc[1] = zero4;
    #pragma unroll
    for (int ks = 0; ks < 8; ks++){
      #pragma unroll
      for (int ns = 0; ns < 2; ns++){
        int n_l = (wn*2 + ns)*16 + l15;
        u16x8 bfrag = *(const u16x8*)&kpc[n_l*256 + (((ks*4 + qd)) ^ ((n_l & 7)*4))*8];
        sc[ns] = mfma16(afrag[ks], bfrag, sc[ns]);
      }
    }

    // ---- mask bias + online softmax (wave-local, own half) ----
    float sEff[2][4];
    #pragma unroll
    for (int ns = 0; ns < 2; ns++){
      int n = n0 + (wn*2 + ns)*16 + l15;
      bool inv = (n >= CNQ);
      bool isEx = (n == CHW);
      int cm = 0;
      if (!inv && !isEx) cm = maskb[n];
      #pragma unroll
      for (int r = 0; r < 4; r++){
        float s = sc[ns][r];
        float se;
        if (inv)        se = -1e30f;
        else if (isEx)  se = s;
        else            se = (rowAllowed[r] & cm) ? s : s - 1e9f;
        sEff[ns][r] = se;
      }
    }
    float al[4], nm[4];
    #pragma unroll
    for (int r = 0; r < 4; r++){
      float tm = fmaxf(sEff[0][r], sEff[1][r]);
      #pragma unroll
      for (int d = 1; d < 16; d <<= 1) tm = fmaxf(tm, __shfl_xor(tm, d, 16));
      float newm = fmaxf(mi[r], tm);
      al[r] = (mi[r] < -1e29f) ? 0.f : __expf(fmaxf(mi[r] - newm, -88.f));
      nm[r] = newm; mi[r] = newm;
    }
    #pragma unroll
    for (int r = 0; r < 4; r++){
      float rs = 0.f;
      int prow = wm*16 + qd*4 + r;
      #pragma unroll
      for (int ns = 0; ns < 2; ns++){
        float p = __expf(fmaxf(sEff[ns][r] - nm[r], -88.f));
        rs += p;
        int ccol = (wn*2 + ns)*16 + l15;
        p_tile[prow*64 + ((ccol >> 3) ^ (prow & 7))*8 + (ccol & 7)] = f2b(p);
      }
      #pragma unroll
      for (int d = 1; d < 16; d <<= 1) rs += __shfl_xor(rs, d, 16);
      li[r] = li[r]*al[r] + rs;
    }
    // P writes/reads are wave-private regions: no barrier, just drain LDS.
    asm volatile("s_waitcnt lgkmcnt(0)" ::: "memory");

    // ---- rescale T, then T += P·Vtile over this wave's 32-column half ----
    #pragma unroll
    for (int ds = 0; ds < 16; ds++){
      #pragma unroll
      for (int r = 0; r < 4; r++) O[ds][r] *= al[r];
    }
    {
      int prow2 = wm*16 + l15;
      u16x8 pf = *(const u16x8*)&p_tile[prow2*64 + (((wn*4 + qd)) ^ (prow2 & 7))*8];
      #pragma unroll
      for (int ds = 0; ds < 16; ds++){
        int c = ds*16 + l15;
        u16x8 vf = *(const u16x8*)&ktc[c*64 + (((wn*4 + qd)) ^ (c & 7))*8];
        O[ds] = mfma16(pf, vf, O[ds]);
      }
    }

    // ---- WRITE staged tile nt+1 into buf[cur^1] ----
    if (havenext){
      #pragma unroll
      for (int i = 0; i < 4; i++){
        int uu = su + 8*i;
        *(u16x8*)&kpn[srow*256 + (uu ^ ((srow & 7)*4))*8] = kreg[i];
      }
      #pragma unroll
      for (int j = 0; j < 4; j++){
        int c = (t >> 3) + 64*j;
        u16x8 v;
        if (nvalid2) v = cvt8(vreg[2*j], vreg[2*j+1]);
        else { v = zero8(); if (vu == 0) v[0] = exv[j]; }
        *(u16x8*)&ktn[c*64 + (vu ^ (c & 7))*8] = v;
      }
    }
    __syncthreads();   // buf[cur] reads done + buf[cur^1] writes visible
  }

  // ---- merge the two N-halves (flash-decoding in-block merge) ----
  int* qlds = (int*)maskb;            // mask no longer needed
  if (t < NQP) qlds[t] = qids[b*160 + t];
  if (l15 == 0){
    #pragma unroll
    for (int r = 0; r < 4; r++){
      mlx[(((wm*2 + wn)*16) + qd*4 + r)*2 + 0] = mi[r];
      mlx[(((wm*2 + wn)*16) + qd*4 + r)*2 + 1] = li[r];
    }
  }
  __syncthreads();
  float alpha[4], linv[4];
  #pragma unroll
  for (int r = 0; r < 4; r++){
    float mo = mlx[(((wm*2 + (1 - wn))*16) + qd*4 + r)*2 + 0];
    float lo = mlx[(((wm*2 + (1 - wn))*16) + qd*4 + r)*2 + 1];
    float ms = fmaxf(mi[r], mo);
    float aS = (mi[r] < -1e29f) ? 0.f : __expf(mi[r] - ms);
    float aO = (mo    < -1e29f) ? 0.f : __expf(mo - ms);
    float ls = li[r]*aS + lo*aO;
    alpha[r] = aS;
    linv[r] = (ls > 0.f) ? (1.0f / ls) : 0.f;
  }
  float* Tsum = (float*)smem;         // 64KB f32 scratch spanning kp0+kt0
  if (wn == 1){
    #pragma unroll
    for (int ds = 0; ds < 16; ds++){
      #pragma unroll
      for (int r = 0; r < 4; r++)
        Tsum[(wm*16 + qd*4 + r)*256 + ds*16 + l15] = O[ds][r]*alpha[r];
    }
  }
  __syncthreads();
  if (wn == 0){
    #pragma unroll
    for (int ds = 0; ds < 16; ds++){
      #pragma unroll
      for (int r = 0; r < 4; r++)
        O[ds][r] = (O[ds][r]*alpha[r] + Tsum[(wm*16 + qd*4 + r)*256 + ds*16 + l15]) * linv[r];
    }
  }
  __syncthreads();                    // Tsum reads done before bf16 overwrite
  if (wn == 0){
    #pragma unroll
    for (int ds = 0; ds < 16; ds++){
      #pragma unroll
      for (int r = 0; r < 4; r++){
        int prow = wm*16 + qd*4 + r;
        int ccol = ds*16 + l15;
        kp0[prow*256 + ((ccol >> 3) ^ ((prow & 7)*4))*8 + (ccol & 7)] = f2b(O[ds][r]);
      }
    }
  }
  __syncthreads();
  u16x8 tfrag[8];
  {
    int arl = wm*16 + l15;
    #pragma unroll
    for (int ks = 0; ks < 8; ks++)
      tfrag[ks] = *(const u16x8*)&kp0[arl*256 + (((ks*4 + qd)) ^ ((arl & 7)*4))*8];
  }
  // ---- final projection F = T_norm · Wv^T, ds split between halves ----
  f32x4 F[8];
  #pragma unroll
  for (int i = 0; i < 8; i++) F[i] = zero4;
  #pragma unroll
  for (int ks = 0; ks < 8; ks++){
    #pragma unroll
    for (int ds = 0; ds < 8; ds++){
      int dsg = wn*8 + ds;
      const float* wr = Wv + (long)(dsg*16 + l15)*CC + ks*32 + qd*8;
      f32x4 w0 = *(const f32x4*)wr;
      f32x4 w1 = *(const f32x4*)(wr + 4);
      F[ds] = mfma16(tfrag[ks], cvt8(w0, w1), F[ds]);
    }
  }

  // ---- epilogue: f32 img_out + f32 query rows (ds-half per wave) ----
  int qix[4];
  #pragma unroll
  for (int r = 0; r < 4; r++){
    int m = m0 + wm*16 + qd*4 + r;
    int f = -1;
    for (int i = 0; i < NQP; i++) if (qlds[i] == m){ f = i; break; }
    qix[r] = f;
  }
  float* oi = out_img + (long)b*257*CHW;
  const float* fi = imgf + (long)b*CC*CHW;
  int mb = m0 + wm*16 + qd*4;
  #pragma unroll
  for (int ds = 0; ds < 8; ds++){
    int d = (wn*8 + ds)*16 + l15;
    f32x4 ivals = *(const f32x4*)(fi + (long)d*CHW + mb);
    f32x4 ovals;
    #pragma unroll
    for (int r = 0; r < 4; r++){
      float v = F[ds][r] + ivals[r];
      ovals[r] = v;
      if (qix[r] >= 0) qbuf[((long)b*NQP + qix[r])*257 + d] = v;
    }
    *(f32x4*)(oi + (long)d*CHW + mb) = ovals;
  }
}

// ---------------- K5: fused LayerNorm + MLP head (all f32) -------------------
// Wave-cooperative GEMV: each wave owns an output row, lanes read the weight
// row CONTIGUOUSLY (coalesced), 6-level shuffle reduce.
__global__ __launch_bounds__(256) void qhead_k(float* __restrict__ qbuf,
    const float* __restrict__ g, const float* __restrict__ be,
    const float* __restrict__ W1, const float* __restrict__ b1,
    const float* __restrict__ W2, const float* __restrict__ b2){
  int bi = blockIdx.x;
  int t = threadIdx.x, lane = t & 63, w = t >> 6;
  __shared__ __align__(16) float xl[257];
  __shared__ __align__(16) float hl[CHID];
  __shared__ float r1[4], r2[4];
  float* row = qbuf + (long)bi*257;
  float v0 = row[t];
  float v1 = (t == 0) ? row[256] : 0.f;
  float s = v0 + v1;
  #pragma unroll
  for (int d = 1; d < 64; d <<= 1) s += __shfl_xor(s, d, 64);
  if (lane == 0) r1[w] = s;
  __syncthreads();
  float mu = (r1[0]+r1[1]+r1[2]+r1[3]) / 257.f;
  float d0 = v0 - mu;
  float d1 = (t == 0) ? (v1 - mu) : 0.f;
  float vs = d0*d0 + d1*d1;
  #pragma unroll
  for (int d = 1; d < 64; d <<= 1) vs += __shfl_xor(vs, d, 64);
  if (lane == 0) r2[w] = vs;
  __syncthreads();
  float var = (r2[0]+r2[1]+r2[2]+r2[3]) / 257.f;
  float inv = 1.0f / sqrtf(var + 1e-5f);
  xl[t] = d0*inv*g[t] + be[t];
  if (t == 0) xl[256] = d1*inv*g[256] + be[256];
  __syncthreads();
  float x256 = xl[256];
  // ---- layer 1: wave w computes rows h = w, w+4, ... (coalesced W1 reads) ----
  for (int h = w; h < CHID; h += 4){
    const float* wr = W1 + (long)h*257;
    float acc = 0.f;
    #pragma unroll
    for (int j = 0; j < 4; j++)
      acc += wr[lane + j*64] * xl[lane + j*64];
    if (lane == 0) acc += wr[256] * x256;
    #pragma unroll
    for (int d = 1; d < 64; d <<= 1) acc += __shfl_xor(acc, d, 64);
    if (lane == 0) hl[h] = fmaxf(acc + b1[h], 0.f);
  }
  __syncthreads();
  // ---- layer 2: wave w computes rows o = w, w+4, ... (coalesced W2 reads) ----
  for (int o = w; o < 257; o += 4){
    const float* wr = W2 + (long)o*CHID + lane*4;
    const float* hp = hl + lane*4;
    float acc = 0.f;
    #pragma unroll
    for (int j = 0; j < 4; j++){
      f32x4 wv = *(const f32x4*)(wr + j*256);
      f32x4 hv = *(const f32x4*)(hp + j*256);
      acc += wv[0]*hv[0] + wv[1]*hv[1] + wv[2]*hv[2] + wv[3]*hv[3];
    }
    #pragma unroll
    for (int d = 1; d < 64; d <<= 1) acc += __shfl_xor(acc, d, 64);
    if (lane == 0) row[o] = acc + b2[o];
  }
}

// ---------------- launch: input mapping by SIZE (robust to ordering) ---------
extern "C" void kernel_launch(void* const* d_in, const int* in_sizes, int n_in,
                              void* d_out, int out_size, void* d_ws, size_t ws_size,
                              hipStream_t stream){
  (void)out_size; (void)ws_size;
  int idxImg=-1, idxExe=-1, idxMask=-1, idxB1=-1;
  int idx65[2]={-1,-1}; int n65=0;
  int idx263[2]={-1,-1}; int n263=0;
  int idx257[3]={-1,-1,-1}; int n257=0;
  for (int i = 0; i < n_in; i++){
    int s = in_sizes[i];
    if      (s == 4194304) idxImg = i;
    else if (s == 50176)   idxExe = i;
    else if (s == 16384)   idxMask = i;
    else if (s == 1024)    idxB1 = i;
    else if (s == 65536)  { if (n65 < 2)  idx65[n65++] = i; }
    else if (s == 263168) { if (n263 < 2) idx263[n263++] = i; }
    else if (s == 257)    { if (n257 < 3) idx257[n257++] = i; }
  }
  const float* img  = (const float*)d_in[idxImg];
  const float* exe  = (const float*)d_in[idxExe];
  const float* mask = (const float*)d_in[idxMask];
  const float* S    = (const float*)d_in[idx65[0]];   // S before Wv in both dict & sorted order
  const float* Wv   = (const float*)d_in[idx65[1]];
  const float* W1   = (const float*)d_in[idx263[0]];  // W1 before W2 in both orders
  const float* W2   = (const float*)d_in[idx263[1]];
  const float* b1   = (const float*)d_in[idxB1];
  const float *lng, *lnb, *b2;
  if (idxImg == 0){           // dict order: ln_g, ln_b, b2
    lng = (const float*)d_in[idx257[0]];
    lnb = (const float*)d_in[idx257[1]];
    b2  = (const float*)d_in[idx257[2]];
  } else {                    // name-sorted: b2, ln_b, ln_g
    b2  = (const float*)d_in[idx257[0]];
    lnb = (const float*)d_in[idx257[1]];
    lng = (const float*)d_in[idx257[2]];
  }

  char* ws = (char*)d_ws;
  u16*   Xt   = (u16*)(ws + XT_OFF);
  u16*   St   = (u16*)(ws + ST_OFF);
  float* exeF = (float*)(ws + EXE_OFF);
  float* heat = (float*)(ws + HEAT_OFF);
  int*   qids = (int*)(ws + QID_OFF);

  float* out      = (float*)d_out;                       // f32 outputs
  float* out_img  = out;                                 // [4][257][4096]
  float* qbuf     = out + (size_t)CB*257*CHW;            // [4][150][257]
  float* out_crd  = qbuf + (size_t)CB*NQP*257;           // [4][150][2]

  exe_prep_k<<<dim3(CB), dim3(256), 0, stream>>>(exe, exeF, Xt);
  transpose64_k<<<dim3(4, 64, CB), dim3(256), 0, stream>>>(
      img, Xt, CHW, (long)CC*CHW, CC, (long)CNQ*CC);
  transpose64_k<<<dim3(4, 4, 1), dim3(256), 0, stream>>>(
      S, St, CC, 0, CC, 0);
  heat2_k<<<dim3(16, CB), dim3(256), 0, stream>>>(exe, S, img, heat, out_img);
  topk_k<<<dim3(CB), dim3(1024), 0, stream>>>(heat, qids, qbuf, out_crd);
  flash_k<<<dim3(64, CB), dim3(512), 0, stream>>>(
      Xt, St, img, mask, Wv, qids, out_img, qbuf);
  qhead_k<<<dim3(CB*NQP), dim3(256), 0, stream>>>(qbuf, lng, lnb, W1, b1, W2, b2);
}